// Round 5
// baseline (191.816 us; speedup 1.0000x reference)
//
#include <hip/hip_runtime.h>
#include <hip/hip_bf16.h>
#include <math.h>

#define GAMMA 0.05f

typedef __attribute__((ext_vector_type(8))) short bf16x8;
typedef __attribute__((ext_vector_type(4))) float f32x4;

static __device__ __forceinline__ unsigned f32_to_bf16(float x) {
    unsigned u = __float_as_uint(x);
    u += 0x7fffu + ((u >> 16) & 1u);   // RNE
    return u >> 16;
}

static __device__ __forceinline__ void gload_lds16(const void* g, void* l) {
    __builtin_amdgcn_global_load_lds(
        (const __attribute__((address_space(1))) void*)g,
        (__attribute__((address_space(3))) void*)l, 16, 0, 0);
}

// ws layout (bytes):
//   0       : 8 doubles: acc[0]=xx_offdiag, acc[1]=yy_offdiag, acc[2]=xy,
//                        acc[3]=sumW, acc[4]=sumW2          (zeroed each launch)
//   1024    : float ENw[8192]  = W[i]*exp(-g*||N_i||^2)     (32 KB)
//   33792   : float ER [8192]  =      exp(-g*||R_i||^2)     (32 KB)
//   66560   : bf16 Nsw: 32 panels x [2 halves x 256 rows x 128 B]  (2 MB)
//   2163712 : bf16 Rsw: same layout                                 (2 MB)
// Within a 128B half-row: byte ^= (row&7)<<4  (8-slot spread -> conflict-free
// ds_read_b128 when 16 lanes read 16 consecutive rows at one column).

__global__ __launch_bounds__(256) void prep_kernel(
    const float* __restrict__ Nmat, const float* __restrict__ Rmat,
    const float* __restrict__ W,
    float* __restrict__ ENw, float* __restrict__ ER,
    unsigned short* __restrict__ Nsw, unsigned short* __restrict__ Rsw,
    double* __restrict__ acc, int nblkN)
{
    const int isR  = (blockIdx.x >= nblkN) ? 1 : 0;
    const int bloc = blockIdx.x - isR * nblkN;
    const int wrp  = threadIdx.x >> 6;
    const int lane = threadIdx.x & 63;
    const int row  = bloc * 4 + wrp;

    const float* X = isR ? Rmat : Nmat;
    unsigned short* Xsw = isR ? Rsw : Nsw;

    float2 v = *(const float2*)(X + (size_t)row * 128 + lane * 2);
    float s = fmaf(v.x, v.x, v.y * v.y);
    unsigned hbits = f32_to_bf16(v.x) | (f32_to_bf16(v.y) << 16);

    const int kb = lane * 4;                       // byte pos in 256B logical row
    const int hf = kb >> 7;
    const int koff = (kb & 127) ^ ((row & 7) << 4);
    size_t off = ((size_t)(row >> 8) << 16) + ((size_t)hf << 15)
               + ((size_t)(row & 255) << 7) + koff;
    *(unsigned*)((char*)Xsw + off) = hbits;

    #pragma unroll
    for (int o = 32; o > 0; o >>= 1) s += __shfl_down(s, o);

    __shared__ float ws[4], w2s[4];
    if (lane == 0) {
        float e = __expf(-GAMMA * s);
        if (!isR) {
            float w = W[row];
            ENw[row] = w * e;
            ws[wrp] = w; w2s[wrp] = w * w;
        } else {
            ER[row] = e;
        }
    }
    if (!isR) {
        __syncthreads();
        if (threadIdx.x == 0) {
            atomicAdd(&acc[3], (double)(ws[0] + ws[1] + ws[2] + ws[3]));
            atomicAdd(&acc[4], (double)(w2s[0] + w2s[1] + w2s[2] + w2s[3]));
        }
    }
}

// One block = 256x256 tile, 512 threads (8 waves, 2x4), wave tile 128x64.
// LDS 128KB: A[2 halves][256][128B] at 0, B same at 65536. Staged with
// global_load_lds (linear; global image pre-swizzled). Half-K pipelined via
// counted vmcnt(8) + raw s_barrier. Diagonal elements zeroed (added exactly
// in finalize). mode 0: N,N upper-tri x2 ; 1: R,R upper-tri x2 ; 2: N,R full.
__global__ __launch_bounds__(512, 2) void mmd_mfma_kernel(
    const unsigned short* __restrict__ Nsw, const unsigned short* __restrict__ Rsw,
    const float* __restrict__ ENw, const float* __restrict__ ER,
    double* __restrict__ acc3)
{
    const int mode = blockIdx.z;
    const int bi = blockIdx.y, bj = blockIdx.x;
    if (mode < 2 && bj < bi) return;

    const unsigned short *A, *B; const float *EA, *EB;
    if (mode == 0)      { A = Nsw; B = Nsw; EA = ENw; EB = ENw; }
    else if (mode == 1) { A = Rsw; B = Rsw; EA = ER;  EB = ER;  }
    else                { A = Nsw; B = Rsw; EA = ENw; EB = ER;  }

    const float scale = (mode < 2 && bj > bi) ? 2.0f : 1.0f;
    const bool diagblk = (mode < 2 && bi == bj);

    __shared__ __align__(16) char lds[131072];
    __shared__ double red[8];

    const int tid  = threadIdx.x;
    const int lane = tid & 63;
    const int wv   = tid >> 6;

    const char* gA = (const char*)A + ((size_t)bi << 16);
    const char* gB = (const char*)B + ((size_t)bj << 16);

    // ---- stage: h1 group (8 loads/thread-pair region), then h2 group ----
    #pragma unroll
    for (int it = 0; it < 4; ++it) {
        int c = (wv * 4 + it) * 1024;
        gload_lds16(gA + c + lane * 16, lds + c);                    // A h1
        gload_lds16(gB + c + lane * 16, lds + 65536 + c);            // B h1
    }
    __builtin_amdgcn_sched_barrier(0);
    #pragma unroll
    for (int it = 0; it < 4; ++it) {
        int c = (wv * 4 + it) * 1024;
        gload_lds16(gA + 32768 + c + lane * 16, lds + 32768 + c);    // A h2
        gload_lds16(gB + 32768 + c + lane * 16, lds + 98304 + c);    // B h2
    }
    __builtin_amdgcn_sched_barrier(0);
    asm volatile("s_waitcnt vmcnt(8)" ::: "memory");   // h1 (oldest 8) done
    __builtin_amdgcn_s_barrier();
    __builtin_amdgcn_sched_barrier(0);

    const int wm = wv >> 2;          // 0..1 : 128-row half
    const int wn = wv & 3;           // 0..3 : 64-col quarter
    const int lg = lane >> 4;        // 0..3
    const int lr = lane & 15;
    const int swz = (lr & 7) << 4;   // row-XOR (row&7 == lr&7 for 16-aligned bases)

    f32x4 acc[8][4];
    #pragma unroll
    for (int mi = 0; mi < 8; ++mi)
        #pragma unroll
        for (int nj = 0; nj < 4; ++nj) acc[mi][nj] = (f32x4){0.f,0.f,0.f,0.f};

    #define DO_KS(ks)                                                          \
    {                                                                          \
        const int hb   = ((ks) >> 1) * 32768;                                  \
        const int koff = ((((ks) & 1) * 64 + lg * 16) ^ swz);                  \
        bf16x8 af[8], bfr[4];                                                  \
        _Pragma("unroll")                                                      \
        for (int mi = 0; mi < 8; ++mi) {                                       \
            int r = wm * 128 + mi * 16 + lr;                                   \
            af[mi] = *(const bf16x8*)(lds + hb + r * 128 + koff);              \
        }                                                                      \
        _Pragma("unroll")                                                      \
        for (int nj = 0; nj < 4; ++nj) {                                       \
            int r = wn * 64 + nj * 16 + lr;                                    \
            bfr[nj] = *(const bf16x8*)(lds + 65536 + hb + r * 128 + koff);     \
        }                                                                      \
        _Pragma("unroll")                                                      \
        for (int mi = 0; mi < 8; ++mi)                                         \
            _Pragma("unroll")                                                  \
            for (int nj = 0; nj < 4; ++nj)                                     \
                acc[mi][nj] = __builtin_amdgcn_mfma_f32_16x16x32_bf16(         \
                    af[mi], bfr[nj], acc[mi][nj], 0, 0, 0);                    \
    }

    DO_KS(0)
    DO_KS(1)
    asm volatile("s_waitcnt vmcnt(0)" ::: "memory");   // h2 writes landed
    __builtin_amdgcn_s_barrier();
    __builtin_amdgcn_sched_barrier(0);
    DO_KS(2)
    DO_KS(3)
    #undef DO_KS

    // ---- epilogue: sum_ij EA_i * EB_j * exp(2*gamma*g_ij), diag zeroed ----
    float eb[4];
    #pragma unroll
    for (int nj = 0; nj < 4; ++nj) eb[nj] = EB[bj * 256 + wn * 64 + nj * 16 + lr];

    float part = 0.f;
    if (!diagblk) {
        #pragma unroll
        for (int mi = 0; mi < 8; ++mi) {
            #pragma unroll
            for (int r = 0; r < 4; ++r) {
                float ea = EA[bi * 256 + wm * 128 + mi * 16 + lg * 4 + r];
                float rowsum = 0.f;
                #pragma unroll
                for (int nj = 0; nj < 4; ++nj)
                    rowsum = fmaf(eb[nj], __expf(2.0f * GAMMA * acc[mi][nj][r]), rowsum);
                part = fmaf(ea, rowsum, part);
            }
        }
    } else {
        #pragma unroll
        for (int mi = 0; mi < 8; ++mi) {
            #pragma unroll
            for (int r = 0; r < 4; ++r) {
                int ci = wm * 128 + mi * 16 + lg * 4 + r;
                float ea = EA[bi * 256 + ci];
                float rowsum = 0.f;
                #pragma unroll
                for (int nj = 0; nj < 4; ++nj) {
                    float e = __expf(2.0f * GAMMA * acc[mi][nj][r]);
                    if (ci == wn * 64 + nj * 16 + lr) e = 0.f;   // diag exact later
                    rowsum = fmaf(eb[nj], e, rowsum);
                }
                part = fmaf(ea, rowsum, part);
            }
        }
    }
    part *= scale;

    double dp = (double)part;
    #pragma unroll
    for (int o = 32; o > 0; o >>= 1) dp += __shfl_down(dp, o);
    if (lane == 0) red[wv] = dp;
    __syncthreads();
    if (tid == 0) {
        double t = 0.0;
        #pragma unroll
        for (int i = 0; i < 8; ++i) t += red[i];
        atomicAdd(&acc3[mode], t);
    }
}

__global__ void finalize_kernel(const double* __restrict__ acc,
                                float* __restrict__ out, int n, int m) {
    if (threadIdx.x == 0) {
        double S = acc[3], S2 = acc[4];
        double xx = (acc[0] + S2) / (S * S);
        double yy = (acc[1] + (double)m) / ((double)m * (double)m);
        double xy = acc[2] / (S * (double)m);
        out[0] = (float)sqrt(fmax(xx + yy - 2.0 * xy, 0.0));
    }
}

extern "C" void kernel_launch(void* const* d_in, const int* in_sizes, int n_in,
                              void* d_out, int out_size, void* d_ws, size_t ws_size,
                              hipStream_t stream) {
    const float* Nmat = (const float*)d_in[0];
    const float* Rmat = (const float*)d_in[1];
    const float* W    = (const float*)d_in[2];
    float* out = (float*)d_out;

    const int n = in_sizes[2];            // 8192
    const int d = in_sizes[0] / n;        // 128
    const int m = in_sizes[1] / d;        // 8192

    double* acc         = (double*)d_ws;
    float* ENw          = (float*)((char*)d_ws + 1024);
    float* ER           = (float*)((char*)d_ws + 33792);
    unsigned short* Nsw = (unsigned short*)((char*)d_ws + 66560);
    unsigned short* Rsw = (unsigned short*)((char*)d_ws + 66560 + 2097152);

    hipMemsetAsync(d_ws, 0, 64, stream);

    prep_kernel<<<(n + m) / 4, 256, 0, stream>>>(Nmat, Rmat, W, ENw, ER, Nsw, Rsw, acc, n / 4);

    dim3 grid(m / 256, n / 256, 3);
    mmd_mfma_kernel<<<grid, 512, 0, stream>>>(Nsw, Rsw, ENw, ER, acc);

    finalize_kernel<<<1, 64, 0, stream>>>(acc, out, n, m);
}

// Round 8
// 134.574 us; speedup vs baseline: 1.4254x; 1.4254x over previous
//
#include <hip/hip_runtime.h>
#include <hip/hip_bf16.h>
#include <math.h>

#define GAMMA 0.05f
#define NP 32          // 8192/256 panels per matrix
#define SYM 528        // NP*(NP+1)/2

typedef __attribute__((ext_vector_type(8))) short bf16x8;
typedef __attribute__((ext_vector_type(4))) float f32x4;

static __device__ __forceinline__ unsigned f32_to_bf16(float x) {
    unsigned u = __float_as_uint(x);
    u += 0x7fffu + ((u >> 16) & 1u);   // RNE
    return u >> 16;
}

static __device__ __forceinline__ void gload_lds16(const void* g, void* l) {
    __builtin_amdgcn_global_load_lds(
        (const __attribute__((address_space(1))) void*)g,
        (__attribute__((address_space(3))) void*)l, 16, 0, 0);
}

// ws layout (bytes):
//   0       : 3 doubles: acc[0]=xx_offdiag, acc[1]=yy_offdiag, acc[2]=xy
//   1024    : float ENw[8192]  = W[i]*exp(-g*||N_i||^2)     (32 KB)
//   33792   : float ER [8192]  =      exp(-g*||R_i||^2)     (32 KB)
//   66560   : bf16 Nsw: 32 panels x [2 halves x 256 rows x 128 B]  (2 MB)
//   2163712 : bf16 Rsw: same layout                                 (2 MB)
// Within a 128B half-row: byte ^= (row&7)<<4  (8-slot spread -> conflict-free
// ds_read_b128 when 16 lanes read 16 consecutive rows at one column).

__global__ __launch_bounds__(256) void prep_kernel(
    const float* __restrict__ Nmat, const float* __restrict__ Rmat,
    const float* __restrict__ W,
    float* __restrict__ ENw, float* __restrict__ ER,
    unsigned short* __restrict__ Nsw, unsigned short* __restrict__ Rsw,
    int nblkN)
{
    const int isR  = (blockIdx.x >= nblkN) ? 1 : 0;
    const int bloc = blockIdx.x - isR * nblkN;
    const int wrp  = threadIdx.x >> 6;
    const int lane = threadIdx.x & 63;
    const int row  = bloc * 4 + wrp;

    const float* X = isR ? Rmat : Nmat;
    unsigned short* Xsw = isR ? Rsw : Nsw;

    float2 v = *(const float2*)(X + (size_t)row * 128 + lane * 2);
    float s = fmaf(v.x, v.x, v.y * v.y);
    unsigned hbits = f32_to_bf16(v.x) | (f32_to_bf16(v.y) << 16);

    const int kb = lane * 4;                       // byte pos in 256B logical row
    const int hf = kb >> 7;
    const int koff = (kb & 127) ^ ((row & 7) << 4);
    size_t off = ((size_t)(row >> 8) << 16) + ((size_t)hf << 15)
               + ((size_t)(row & 255) << 7) + koff;
    *(unsigned*)((char*)Xsw + off) = hbits;

    #pragma unroll
    for (int o = 32; o > 0; o >>= 1) s += __shfl_down(s, o);

    if (lane == 0) {
        float e = __expf(-GAMMA * s);
        if (!isR) ENw[row] = W[row] * e;
        else      ER[row]  = e;
    }
}

// One block = 256x256 tile, 512 threads (8 waves, 2x4), wave tile 128x64.
// Exact 2080-block 1D grid: [0,528) mode0 upper-tri, [528,1056) mode1,
// [1056,2080) mode2 full 32x32. LDS 128KB: A[2 halves][256][128B] | B same.
// Staged via global_load_lds (linear; global pre-swizzled). Half-K pipelined
// with counted vmcnt(8) + raw s_barrier. Diagonal added exactly in finalize.
__global__ __launch_bounds__(512, 2) void mmd_mfma_kernel(
    const unsigned short* __restrict__ Nsw, const unsigned short* __restrict__ Rsw,
    const float* __restrict__ ENw, const float* __restrict__ ER,
    double* __restrict__ acc3)
{
    // ---- unrank block id -> (mode, bi, bj) ----
    int mode, bi, bj;
    {
        int bid = blockIdx.x;
        if (bid < 2 * SYM) {
            mode = (bid >= SYM) ? 1 : 0;
            int t = bid - mode * SYM;
            int i = (int)(32.5f - sqrtf(1056.25f - 2.0f * (float)t));
            if (i < 0) i = 0;
            while ((i + 1) * NP - ((i + 1) * i) / 2 <= t) ++i;
            while (i * NP - (i * (i - 1)) / 2 > t) --i;
            bi = i;
            bj = i + (t - (i * NP - (i * (i - 1)) / 2));
        } else {
            mode = 2;
            int t = bid - 2 * SYM;
            bi = t >> 5;
            bj = t & 31;
        }
    }

    const unsigned short *A, *B; const float *EA, *EB;
    if (mode == 0)      { A = Nsw; B = Nsw; EA = ENw; EB = ENw; }
    else if (mode == 1) { A = Rsw; B = Rsw; EA = ER;  EB = ER;  }
    else                { A = Nsw; B = Rsw; EA = ENw; EB = ER;  }

    const float scale = (mode < 2 && bj > bi) ? 2.0f : 1.0f;
    const bool diagblk = (mode < 2 && bi == bj);

    __shared__ __align__(16) char lds[131072];
    __shared__ double red[8];

    const int tid  = threadIdx.x;
    const int lane = tid & 63;
    const int wv   = tid >> 6;

    const char* gA = (const char*)A + ((size_t)bi << 16);
    const char* gB = (const char*)B + ((size_t)bj << 16);

    // ---- stage: h1 group (8 loads), then h2 group (8 loads) ----
    #pragma unroll
    for (int it = 0; it < 4; ++it) {
        int c = (wv * 4 + it) * 1024;
        gload_lds16(gA + c + lane * 16, lds + c);                    // A h1
        gload_lds16(gB + c + lane * 16, lds + 65536 + c);            // B h1
    }
    __builtin_amdgcn_sched_barrier(0);
    #pragma unroll
    for (int it = 0; it < 4; ++it) {
        int c = (wv * 4 + it) * 1024;
        gload_lds16(gA + 32768 + c + lane * 16, lds + 32768 + c);    // A h2
        gload_lds16(gB + 32768 + c + lane * 16, lds + 98304 + c);    // B h2
    }
    __builtin_amdgcn_sched_barrier(0);
    asm volatile("s_waitcnt vmcnt(8)" ::: "memory");   // h1 (oldest 8) done
    __builtin_amdgcn_s_barrier();
    __builtin_amdgcn_sched_barrier(0);

    const int wm = wv >> 2;          // 0..1 : 128-row half
    const int wn = wv & 3;           // 0..3 : 64-col quarter
    const int lg = lane >> 4;        // 0..3
    const int lr = lane & 15;
    const int swz = (lr & 7) << 4;   // row-XOR (row&7 == lr&7 for 16-aligned bases)

    f32x4 acc[8][4];
    #pragma unroll
    for (int mi = 0; mi < 8; ++mi)
        #pragma unroll
        for (int nj = 0; nj < 4; ++nj) acc[mi][nj] = (f32x4){0.f,0.f,0.f,0.f};

    #define DO_KS(ks)                                                          \
    {                                                                          \
        const int hb   = ((ks) >> 1) * 32768;                                  \
        const int koff = ((((ks) & 1) * 64 + lg * 16) ^ swz);                  \
        bf16x8 af[8], bfr[4];                                                  \
        _Pragma("unroll")                                                      \
        for (int mi = 0; mi < 8; ++mi) {                                       \
            int r = wm * 128 + mi * 16 + lr;                                   \
            af[mi] = *(const bf16x8*)(lds + hb + r * 128 + koff);              \
        }                                                                      \
        _Pragma("unroll")                                                      \
        for (int nj = 0; nj < 4; ++nj) {                                       \
            int r = wn * 64 + nj * 16 + lr;                                    \
            bfr[nj] = *(const bf16x8*)(lds + 65536 + hb + r * 128 + koff);     \
        }                                                                      \
        __builtin_amdgcn_s_setprio(1);                                         \
        _Pragma("unroll")                                                      \
        for (int mi = 0; mi < 8; ++mi)                                         \
            _Pragma("unroll")                                                  \
            for (int nj = 0; nj < 4; ++nj)                                     \
                acc[mi][nj] = __builtin_amdgcn_mfma_f32_16x16x32_bf16(         \
                    af[mi], bfr[nj], acc[mi][nj], 0, 0, 0);                    \
        __builtin_amdgcn_s_setprio(0);                                         \
    }

    DO_KS(0)
    DO_KS(1)
    asm volatile("s_waitcnt vmcnt(0)" ::: "memory");   // h2 writes landed
    __builtin_amdgcn_s_barrier();
    __builtin_amdgcn_sched_barrier(0);
    DO_KS(2)
    DO_KS(3)
    #undef DO_KS

    // ---- epilogue: sum_ij EA_i * EB_j * exp(2*gamma*g_ij), diag zeroed ----
    float eb[4];
    #pragma unroll
    for (int nj = 0; nj < 4; ++nj) eb[nj] = EB[bj * 256 + wn * 64 + nj * 16 + lr];

    float part = 0.f;
    if (!diagblk) {
        #pragma unroll
        for (int mi = 0; mi < 8; ++mi) {
            float4 ea4 = *(const float4*)&EA[bi * 256 + wm * 128 + mi * 16 + lg * 4];
            #pragma unroll
            for (int r = 0; r < 4; ++r) {
                float rowsum = 0.f;
                #pragma unroll
                for (int nj = 0; nj < 4; ++nj)
                    rowsum = fmaf(eb[nj], __expf(2.0f * GAMMA * acc[mi][nj][r]), rowsum);
                part = fmaf(((const float*)&ea4)[r], rowsum, part);
            }
        }
    } else {
        #pragma unroll
        for (int mi = 0; mi < 8; ++mi) {
            float4 ea4 = *(const float4*)&EA[bi * 256 + wm * 128 + mi * 16 + lg * 4];
            #pragma unroll
            for (int r = 0; r < 4; ++r) {
                int ci = wm * 128 + mi * 16 + lg * 4 + r;
                float rowsum = 0.f;
                #pragma unroll
                for (int nj = 0; nj < 4; ++nj) {
                    float e = __expf(2.0f * GAMMA * acc[mi][nj][r]);
                    if (ci == wn * 64 + nj * 16 + lr) e = 0.f;   // diag exact later
                    rowsum = fmaf(eb[nj], e, rowsum);
                }
                part = fmaf(((const float*)&ea4)[r], rowsum, part);
            }
        }
    }
    part *= scale;

    double dp = (double)part;
    #pragma unroll
    for (int o = 32; o > 0; o >>= 1) dp += __shfl_down(dp, o);
    if (lane == 0) red[wv] = dp;
    __syncthreads();
    if (tid == 0) {
        double t = 0.0;
        #pragma unroll
        for (int i = 0; i < 8; ++i) t += red[i];
        atomicAdd(&acc3[mode], t);
    }
}

__global__ __launch_bounds__(256) void finalize_kernel(const float* __restrict__ W,
                                                       const double* __restrict__ acc,
                                                       float* __restrict__ out,
                                                       int n, int m) {
    __shared__ double redS[256], redS2[256];
    double s = 0.0, s2 = 0.0;
    for (int i = threadIdx.x; i < n; i += 256) {
        double w = (double)W[i];
        s += w; s2 += w * w;
    }
    redS[threadIdx.x] = s; redS2[threadIdx.x] = s2;
    __syncthreads();
    for (int stride = 128; stride > 0; stride >>= 1) {
        if (threadIdx.x < stride) {
            redS[threadIdx.x]  += redS[threadIdx.x + stride];
            redS2[threadIdx.x] += redS2[threadIdx.x + stride];
        }
        __syncthreads();
    }
    if (threadIdx.x == 0) {
        double S = redS[0], S2 = redS2[0];
        double xx = (acc[0] + S2) / (S * S);
        double yy = (acc[1] + (double)m) / ((double)m * (double)m);
        double xy = acc[2] / (S * (double)m);
        out[0] = (float)sqrt(fmax(xx + yy - 2.0 * xy, 0.0));
    }
}

extern "C" void kernel_launch(void* const* d_in, const int* in_sizes, int n_in,
                              void* d_out, int out_size, void* d_ws, size_t ws_size,
                              hipStream_t stream) {
    const float* Nmat = (const float*)d_in[0];
    const float* Rmat = (const float*)d_in[1];
    const float* W    = (const float*)d_in[2];
    float* out = (float*)d_out;

    const int n = in_sizes[2];            // 8192
    const int d = in_sizes[0] / n;        // 128
    const int m = in_sizes[1] / d;        // 8192

    double* acc         = (double*)d_ws;
    float* ENw          = (float*)((char*)d_ws + 1024);
    float* ER           = (float*)((char*)d_ws + 33792);
    unsigned short* Nsw = (unsigned short*)((char*)d_ws + 66560);
    unsigned short* Rsw = (unsigned short*)((char*)d_ws + 66560 + 2097152);

    hipMemsetAsync(d_ws, 0, 64, stream);

    prep_kernel<<<(n + m) / 4, 256, 0, stream>>>(Nmat, Rmat, W, ENw, ER, Nsw, Rsw, n / 4);

    mmd_mfma_kernel<<<2 * SYM + NP * NP, 512, 0, stream>>>(Nsw, Rsw, ENw, ER, acc);

    finalize_kernel<<<1, 256, 0, stream>>>(W, acc, out, n, m);
}